// Round 1
// baseline (97.198 us; speedup 1.0000x reference)
//
#include <hip/hip_runtime.h>
#include <math.h>

#define NN 32
#define TT 1024
#define ROWS 16           // rows of the (i) dimension per block
#define NEG_INIT -3.0e38f // finite sentinel: exp(NEG_INIT - x) flushes to 0, no NaN

// Branchless online logsumexp update: (m,s) <- merge with value v
__device__ __forceinline__ void lse_update(float& m, float& s, float v) {
    float M = fmaxf(m, v);
    s = s * __expf(m - M) + __expf(v - M);
    m = M;
}

__global__ __launch_bounds__(256) void gmsm_kernel(
    const float* __restrict__ time_, const float* __restrict__ loc,
    const float* __restrict__ mu0p, const float* __restrict__ logstd0p,
    const float* __restrict__ cdp, const float* __restrict__ slsp,
    float* __restrict__ out)
{
    const int blocksPerN = TT / ROWS;
    const int n  = blockIdx.x / blocksPerN;
    const int r0 = (blockIdx.x % blocksPerN) * ROWS;

    __shared__ float st[TT];
    __shared__ float sx[TT];
    __shared__ float sy[TT];

    const int tid = threadIdx.x;
    const int jmax = r0 + ROWS;   // largest index touched is i = r0+ROWS-1
    for (int j = tid; j < jmax; j += 256) {
        st[j] = time_[n * TT + j];
        float2 l = ((const float2*)loc)[n * TT + j];
        sx[j] = l.x;
        sy[j] = l.y;
    }
    __syncthreads();

    const float LOG2PI = 1.8378770664093453f;
    const float cd  = cdp[0];
    const float sls = slsp[0];
    const float sp  = logf(1.0f + expf(cd));   // softplus(coeff_decay)
    const float inv_sp = 1.0f / sp;
    const float inv2   = expf(-2.0f * sls);    // exp(-spatial_logstd)^2
    const float Cp     = -(2.0f * sls + LOG2PI);
    const float neg_half_inv2 = -0.5f * inv2;

    const int wave = tid >> 6;
    const int lane = tid & 63;

    for (int rr = wave; rr < ROWS; rr += 4) {
        const int i = r0 + rr;

        if (i == 0) {
            // loglik0: sum_d gaussian_loglik(loc[n,0,d], mu0, logstd0)
            if (lane == 0) {
                float mu0 = mu0p[0], ls0 = logstd0p[0];
                float inv0 = expf(-ls0);
                float dx = (sx[0] - mu0) * inv0;
                float dy = (sy[0] - mu0) * inv0;
                out[n * TT] = -0.5f * (dx * dx + dy * dy) - (2.0f * ls0 + LOG2PI);
            }
            continue;
        }

        const float xi = sx[i], yi = sy[i];

        // Online LSEs over j < i (lane-strided):
        //   LSE1 over v_j = a_j - 0.5*inv2*r2_j    (a_j = t_j / sp)
        //   LSE2 over a_j (monotone non-decreasing per lane -> 1-exp update)
        float m1 = NEG_INIT, s1 = 0.0f;
        float m2 = NEG_INIT, s2 = 0.0f;
        for (int j = lane; j < i; j += 64) {
            float a  = st[j] * inv_sp;
            float dx = sx[j] - xi;
            float dy = sy[j] - yi;
            float v  = fmaf(neg_half_inv2, fmaf(dx, dx, dy * dy), a);
            lse_update(m1, s1, v);
            // monotone update: a >= m2 always (times sorted ascending)
            s2 = s2 * __expf(m2 - a) + 1.0f;
            m2 = a;
        }

        // 64-lane butterfly merge of (m,s) pairs
        #pragma unroll
        for (int off = 1; off < 64; off <<= 1) {
            float om1 = __shfl_xor(m1, off, 64);
            float os1 = __shfl_xor(s1, off, 64);
            float om2 = __shfl_xor(m2, off, 64);
            float os2 = __shfl_xor(s2, off, 64);
            float M1 = fmaxf(m1, om1);
            s1 = s1 * __expf(m1 - M1) + os1 * __expf(om1 - M1);
            m1 = M1;
            float M2 = fmaxf(m2, om2);
            s2 = s2 * __expf(m2 - M2) + os2 * __expf(om2 - M2);
            m2 = M2;
        }

        if (lane == 0) {
            out[n * TT + i] = Cp + (m1 + __logf(s1)) - (m2 + __logf(s2));
        }
    }
}

extern "C" void kernel_launch(void* const* d_in, const int* in_sizes, int n_in,
                              void* d_out, int out_size, void* d_ws, size_t ws_size,
                              hipStream_t stream) {
    const float* time_   = (const float*)d_in[0];  // (N,T,1)
    const float* loc     = (const float*)d_in[1];  // (N,T,2)
    // d_in[2] = input_mag, d_in[3] = input_timediff  -> unused by reference
    const float* mu0     = (const float*)d_in[4];
    const float* logstd0 = (const float*)d_in[5];
    const float* cd      = (const float*)d_in[6];
    const float* sls     = (const float*)d_in[7];
    float* out = (float*)d_out;                    // (N,T) fp32

    dim3 grid(NN * (TT / ROWS));
    gmsm_kernel<<<grid, 256, 0, stream>>>(time_, loc, mu0, logstd0, cd, sls, out);
}

// Round 2
// 79.534 us; speedup vs baseline: 1.2221x; 1.2221x over previous
//
#include <hip/hip_runtime.h>
#include <math.h>

#define NN 32
#define TT 1024
#define ROWS 16
#define PAIRS (TT / ROWS / 2)   // 32 pair-blocks per n; pair tile p with tile 63-p

__global__ __launch_bounds__(256) void gmsm_kernel(
    const float* __restrict__ time_, const float* __restrict__ loc,
    const float* __restrict__ mu0p, const float* __restrict__ logstd0p,
    const float* __restrict__ cdp, const float* __restrict__ slsp,
    float* __restrict__ out)
{
    const int n = blockIdx.x / PAIRS;
    const int p = blockIdx.x % PAIRS;

    const int loTile = p * ROWS;              // rows [loTile, loTile+ROWS)
    const int hiTile = TT - (p + 1) * ROWS;   // rows [hiTile, hiTile+ROWS)
    const int jmax   = hiTile + ROWS;         // largest index touched + 1

    __shared__ float sa[TT];   // a_j = t_j / softplus(coeff_decay)
    __shared__ float sx[TT];
    __shared__ float sy[TT];

    const float LOG2PI = 1.8378770664093453f;
    const float cd  = cdp[0];
    const float sls = slsp[0];
    const float inv_sp = 1.0f / logf(1.0f + expf(cd));   // 1/softplus
    const float neg_half_inv2 = -0.5f * expf(-2.0f * sls);
    const float Cp = -(2.0f * sls + LOG2PI);

    const int tid = threadIdx.x;
    for (int j = tid; j < jmax; j += 256) {
        sa[j] = time_[n * TT + j] * inv_sp;
        float2 l = ((const float2*)loc)[n * TT + j];
        sx[j] = l.x;
        sy[j] = l.y;
    }
    __syncthreads();

    const int wave = tid >> 6;
    const int lane = tid & 63;

    // 2*ROWS rows per block; each wave gets 4 low-tile + 4 high-tile rows.
    for (int k = wave; k < 2 * ROWS; k += 4) {
        const int i = (k < ROWS) ? (loTile + k) : (hiTile + (k - ROWS));

        if (i == 0) {
            if (lane == 0) {
                float mu0 = mu0p[0], ls0 = logstd0p[0];
                float inv0 = expf(-ls0);
                float dx = (sx[0] - mu0) * inv0;
                float dy = (sy[0] - mu0) * inv0;
                out[n * TT] = -0.5f * (dx * dx + dy * dy) - (2.0f * ls0 + LOG2PI);
            }
            continue;
        }

        const float xi = sx[i], yi = sy[i];
        const float base = sa[i - 1];   // max of a_j over j<i (times sorted)

        // out[i] = Cp + log( sum_{j<i} exp(a_j - base - 0.5*inv2*r2_j) )
        //             - log( sum_{j<i} exp(a_j - base) )
        // base-shift makes both sums overflow-free; denominator >= 1 (j=i-1 term).
        float s1 = 0.0f, s2 = 0.0f;
        for (int j = lane; j < i; j += 64) {
            float am = sa[j] - base;
            float dx = sx[j] - xi;
            float dy = sy[j] - yi;
            float r2 = fmaf(dx, dx, dy * dy);
            s2 += __expf(am);
            s1 += __expf(fmaf(neg_half_inv2, r2, am));
        }

        #pragma unroll
        for (int off = 1; off < 64; off <<= 1) {
            s1 += __shfl_xor(s1, off, 64);
            s2 += __shfl_xor(s2, off, 64);
        }

        if (lane == 0) {
            out[n * TT + i] = Cp + __logf(s1) - __logf(s2);
        }
    }
}

extern "C" void kernel_launch(void* const* d_in, const int* in_sizes, int n_in,
                              void* d_out, int out_size, void* d_ws, size_t ws_size,
                              hipStream_t stream) {
    const float* time_   = (const float*)d_in[0];  // (N,T,1)
    const float* loc     = (const float*)d_in[1];  // (N,T,2)
    // d_in[2] = input_mag, d_in[3] = input_timediff -> unused by reference
    const float* mu0     = (const float*)d_in[4];
    const float* logstd0 = (const float*)d_in[5];
    const float* cd      = (const float*)d_in[6];
    const float* sls     = (const float*)d_in[7];
    float* out = (float*)d_out;                    // (N,T) fp32

    dim3 grid(NN * PAIRS);
    gmsm_kernel<<<grid, 256, 0, stream>>>(time_, loc, mu0, logstd0, cd, sls, out);
}